// Round 1
// baseline (11321.898 us; speedup 1.0000x reference)
//
#include <hip/hip_runtime.h>
#include <hip/hip_bf16.h>

#define BSZ 16
#define NCLS 80

// output layout (f32 elements)
#define RO 10752000   // reg/dist offset   = 16*80*8400
#define AO 11289600   // anchors offset    = RO + 16*8400*4
#define SO 11306400   // strides offset    = AO + 8400*2

struct Lvl {
  const float *feat, *cfw, *cfb, *rfw, *rfb, *ccw, *ccb, *rcw, *rcb, *pcw, *pcb, *prw, *prb;
  int C, H, W, HW, pos_off;
  long tcr_off;  // element offset into tc/tr buffers
};

struct Args {
  Lvl l[3];
  float *avg, *gc, *gr;       // [3][BSZ][768] each
  __hip_bfloat16 *tc, *tr;    // concatenated per-level [B,C,HW] bf16
  float *out;
};

__device__ __forceinline__ float sigm(float x) { return 1.f / (1.f + __expf(-x)); }

__device__ __forceinline__ int lvl_of(int bid, int s1, int s2) { return bid >= s2 ? 2 : (bid >= s1 ? 1 : 0); }
__device__ __forceinline__ int loc_of(int bid, int l, int s1, int s2) { return bid - (l == 2 ? s2 : (l == 1 ? s1 : 0)); }

__global__ __launch_bounds__(256) void k_anchor(float* out) {
  int g = blockIdx.x * 256 + threadIdx.x;
  if (g >= 8400) return;
  int l = g < 400 ? 0 : (g < 2000 ? 1 : 2);
  int off = l == 0 ? 0 : (l == 1 ? 400 : 2000);
  int w = l == 0 ? 20 : (l == 1 ? 40 : 80);
  float s = l == 0 ? 32.f : (l == 1 ? 16.f : 8.f);
  int p = g - off;
  int x = p % w, y = p / w;
  out[AO + 2 * g]     = x + 0.5f;
  out[AO + 2 * g + 1] = y + 0.5f;
  out[SO + g]         = s;
}

__global__ __launch_bounds__(256) void k_avg(Args a, int s1, int s2) {
  int bid = blockIdx.x;
  int l = lvl_of(bid, s1, s2);
  int loc = loc_of(bid, l, s1, s2);
  const Lvl& L = a.l[l];
  int c = loc % L.C, b = loc / L.C;
  const float* src = L.feat + (size_t)(b * L.C + c) * L.HW;
  float s = 0.f;
  for (int i = threadIdx.x; i < L.HW; i += 256) s += src[i];
  __shared__ float red[256];
  red[threadIdx.x] = s;
  __syncthreads();
  for (int o = 128; o > 0; o >>= 1) {
    if (threadIdx.x < o) red[threadIdx.x] += red[threadIdx.x + o];
    __syncthreads();
  }
  if (threadIdx.x == 0) a.avg[(l * BSZ + b) * 768 + c] = red[0] / (float)L.HW;
}

__global__ __launch_bounds__(256) void k_gate(Args a, int s1, int s2) {
  int bid = blockIdx.x;
  int l = lvl_of(bid, s1, s2);
  int loc = loc_of(bid, l, s1, s2);
  const Lvl& L = a.l[l];
  int co = loc % L.C, b = loc / L.C;
  const float* av = a.avg + (l * BSZ + b) * 768;
  float sc = 0.f, sr = 0.f;
  for (int ci = threadIdx.x; ci < L.C; ci += 256) {
    float v = av[ci];
    sc += L.cfw[(size_t)co * L.C + ci] * v;
    sr += L.rfw[(size_t)co * L.C + ci] * v;
  }
  __shared__ float rc[256], rr[256];
  rc[threadIdx.x] = sc; rr[threadIdx.x] = sr;
  __syncthreads();
  for (int o = 128; o > 0; o >>= 1) {
    if (threadIdx.x < o) { rc[threadIdx.x] += rc[threadIdx.x + o]; rr[threadIdx.x] += rr[threadIdx.x + o]; }
    __syncthreads();
  }
  if (threadIdx.x == 0) {
    a.gc[(l * BSZ + b) * 768 + co] = sigm(rc[0] + L.cfb[co]);
    a.gr[(l * BSZ + b) * 768 + co] = sigm(rr[0] + L.rfb[co]);
  }
}

// fused dual-branch 1x1 conv: tc = silu(ccw @ (feat*gc) + ccb) + feat ; tr = silu(rcw @ (feat*gr) + rcb)
__global__ __launch_bounds__(256) void k_conv1(Args a, int s1, int s2) {
  int bid = blockIdx.x;
  int l = lvl_of(bid, s1, s2);
  int loc = loc_of(bid, l, s1, s2);
  const Lvl& L = a.l[l];
  int pt = (L.HW + 255) / 256;
  int ptile = loc % pt;
  int t = loc / pt;
  int cochunks = L.C / 16;
  int cc = t % cochunks;
  int b = t / cochunks;
  int p = ptile * 256 + threadIdx.x;
  bool ok = p < L.HW;
  int pp = ok ? p : 0;
  int co0 = cc * 16;

  const float* fbase = L.feat + (size_t)b * L.C * L.HW + pp;
  const float* gcb = a.gc + (l * BSZ + b) * 768;
  const float* grb = a.gr + (l * BSZ + b) * 768;

  float accC[16], accR[16];
#pragma unroll
  for (int j = 0; j < 16; j++) { accC[j] = 0.f; accR[j] = 0.f; }

  const int C = L.C;
#pragma unroll 4
  for (int ci = 0; ci < C; ci++) {
    float f = fbase[(size_t)ci * L.HW];
    float fc = f * gcb[ci];
    float fr = f * grb[ci];
    const float* wc = L.ccw + (size_t)co0 * C + ci;
    const float* wr = L.rcw + (size_t)co0 * C + ci;
#pragma unroll
    for (int j = 0; j < 16; j++) {
      accC[j] += wc[(size_t)j * C] * fc;
      accR[j] += wr[(size_t)j * C] * fr;
    }
  }
  if (ok) {
#pragma unroll
    for (int j = 0; j < 16; j++) {
      float res = fbase[(size_t)(co0 + j) * L.HW];
      float xc = accC[j] + L.ccb[co0 + j];
      float tcv = xc * sigm(xc) + res;
      float xr = accR[j] + L.rcb[co0 + j];
      float trv = xr * sigm(xr);
      size_t o = (size_t)L.tcr_off + ((size_t)(b * L.C + co0 + j)) * L.HW + p;
      a.tc[o] = __float2bfloat16(tcv);
      a.tr[o] = __float2bfloat16(trv);
    }
  }
}

// 3x3 cls pred conv + sigmoid, 16 out channels per thread
__global__ __launch_bounds__(256) void k_conv3c(Args a, int s1, int s2) {
  int bid = blockIdx.x;
  int l = lvl_of(bid, s1, s2);
  int loc = loc_of(bid, l, s1, s2);
  const Lvl& L = a.l[l];
  int pt = (L.HW + 255) / 256;
  int ptile = loc % pt;
  int t = loc / pt;
  int oc = t % 5;
  int b = t / 5;
  int o0 = oc * 16;
  int p = ptile * 256 + threadIdx.x;
  bool ok = p < L.HW;
  int pp = ok ? p : 0;
  int x = pp % L.W, y = pp / L.W;

  int offs[9];
  float mf[9];
#pragma unroll
  for (int ky = 0; ky < 3; ky++)
#pragma unroll
    for (int kx = 0; kx < 3; kx++) {
      int yy = y + ky - 1, xx = x + kx - 1;
      bool v = (yy >= 0 && yy < L.H && xx >= 0 && xx < L.W);
      int yc = min(max(yy, 0), L.H - 1);
      int xc = min(max(xx, 0), L.W - 1);
      offs[ky * 3 + kx] = yc * L.W + xc - pp;
      mf[ky * 3 + kx] = v ? 1.f : 0.f;
    }

  const __hip_bfloat16* base = a.tc + (size_t)L.tcr_off + (size_t)b * L.C * L.HW + pp;
  float acc[16];
#pragma unroll
  for (int j = 0; j < 16; j++) acc[j] = L.pcb[o0 + j];

  const int C = L.C;
  for (int ci = 0; ci < C; ci++) {
    float v[9];
#pragma unroll
    for (int k = 0; k < 9; k++)
      v[k] = __bfloat162float(base[(size_t)ci * L.HW + offs[k]]) * mf[k];
    const float* w = L.pcw + ((size_t)o0 * C + ci) * 9;
#pragma unroll
    for (int j = 0; j < 16; j++) {
      const float* wj = w + (size_t)j * C * 9;
#pragma unroll
      for (int k = 0; k < 9; k++) acc[j] += wj[k] * v[k];
    }
  }
  if (ok) {
#pragma unroll
    for (int j = 0; j < 16; j++)
      a.out[(size_t)(b * NCLS + o0 + j) * 8400 + L.pos_off + p] = sigm(acc[j]);
  }
}

// 3x3 reg pred conv (68 ch) + DFL softmax decode, one thread per spatial pos
__global__ __launch_bounds__(64) void k_conv3r(Args a, int s1, int s2) {
  int bid = blockIdx.x;
  int l = lvl_of(bid, s1, s2);
  int loc = loc_of(bid, l, s1, s2);
  const Lvl& L = a.l[l];
  int pt = (L.HW + 63) / 64;
  int ptile = loc % pt;
  int b = loc / pt;
  int p = ptile * 64 + threadIdx.x;
  bool ok = p < L.HW;
  int pp = ok ? p : 0;
  int x = pp % L.W, y = pp / L.W;

  int offs[9];
  float mf[9];
#pragma unroll
  for (int ky = 0; ky < 3; ky++)
#pragma unroll
    for (int kx = 0; kx < 3; kx++) {
      int yy = y + ky - 1, xx = x + kx - 1;
      bool v = (yy >= 0 && yy < L.H && xx >= 0 && xx < L.W);
      int yc = min(max(yy, 0), L.H - 1);
      int xc = min(max(xx, 0), L.W - 1);
      offs[ky * 3 + kx] = yc * L.W + xc - pp;
      mf[ky * 3 + kx] = v ? 1.f : 0.f;
    }

  const __hip_bfloat16* base = a.tr + (size_t)L.tcr_off + (size_t)b * L.C * L.HW + pp;
  float acc[68];
#pragma unroll
  for (int j = 0; j < 68; j++) acc[j] = L.prb[j];

  const int C = L.C;
  for (int ci = 0; ci < C; ci++) {
    float v[9];
#pragma unroll
    for (int k = 0; k < 9; k++)
      v[k] = __bfloat162float(base[(size_t)ci * L.HW + offs[k]]) * mf[k];
    const float* w = L.prw + (size_t)ci * 9;
#pragma unroll
    for (int j = 0; j < 68; j++) {
      const float* wj = w + (size_t)j * C * 9;
#pragma unroll
      for (int k = 0; k < 9; k++) acc[j] += wj[k] * v[k];
    }
  }
  if (ok) {
#pragma unroll
    for (int g4 = 0; g4 < 4; g4++) {
      float mx = acc[g4 * 17];
#pragma unroll
      for (int k = 1; k < 17; k++) mx = fmaxf(mx, acc[g4 * 17 + k]);
      float s = 0.f, d = 0.f;
#pragma unroll
      for (int k = 0; k < 17; k++) {
        float e = __expf(acc[g4 * 17 + k] - mx);
        s += e;
        d += (float)k * e;
      }
      a.out[RO + ((size_t)b * 8400 + L.pos_off + p) * 4 + g4] = d / s;
    }
  }
}

extern "C" void kernel_launch(void* const* d_in, const int* in_sizes, int n_in,
                              void* d_out, int out_size, void* d_ws, size_t ws_size,
                              hipStream_t stream) {
  static const int Cs[3] = {768, 384, 192};
  static const int HHs[3] = {20, 40, 80};
  static const int POs[3] = {0, 400, 2000};
  static const long TOFF[3] = {0, 4915200, 14745600};

  Args a;
  for (int l = 0; l < 3; l++) {
    const float* const* p = (const float* const*)(d_in + l * 13);
    Lvl& L = a.l[l];
    L.feat = p[0];
    L.cfw = p[1]; L.cfb = p[2]; L.rfw = p[3]; L.rfb = p[4];
    L.ccw = p[5]; L.ccb = p[6]; L.rcw = p[7]; L.rcb = p[8];
    L.pcw = p[9]; L.pcb = p[10]; L.prw = p[11]; L.prb = p[12];
    L.C = Cs[l]; L.H = HHs[l]; L.W = HHs[l]; L.HW = HHs[l] * HHs[l];
    L.pos_off = POs[l];
    L.tcr_off = TOFF[l];
  }
  float* ws = (float*)d_ws;
  a.avg = ws;
  a.gc = ws + 3 * BSZ * 768;
  a.gr = ws + 2 * 3 * BSZ * 768;
  a.tc = (__hip_bfloat16*)(ws + 3 * 3 * BSZ * 768);
  a.tr = a.tc + 34406400;
  a.out = (float*)d_out;

  hipLaunchKernelGGL(k_anchor, dim3(33), dim3(256), 0, stream, a.out);

  int s1 = BSZ * 768, s2 = s1 + BSZ * 384, tot = s2 + BSZ * 192;
  hipLaunchKernelGGL(k_avg, dim3(tot), dim3(256), 0, stream, a, s1, s2);
  hipLaunchKernelGGL(k_gate, dim3(tot), dim3(256), 0, stream, a, s1, s2);

  int c1_0 = BSZ * (768 / 16) * ((400 + 255) / 256);
  int c1_1 = BSZ * (384 / 16) * ((1600 + 255) / 256);
  int c1_2 = BSZ * (192 / 16) * ((6400 + 255) / 256);
  hipLaunchKernelGGL(k_conv1, dim3(c1_0 + c1_1 + c1_2), dim3(256), 0, stream, a, c1_0, c1_0 + c1_1);

  int c3_0 = BSZ * 5 * ((400 + 255) / 256);
  int c3_1 = BSZ * 5 * ((1600 + 255) / 256);
  int c3_2 = BSZ * 5 * ((6400 + 255) / 256);
  hipLaunchKernelGGL(k_conv3c, dim3(c3_0 + c3_1 + c3_2), dim3(256), 0, stream, a, c3_0, c3_0 + c3_1);

  int r_0 = BSZ * ((400 + 63) / 64);
  int r_1 = BSZ * ((1600 + 63) / 64);
  int r_2 = BSZ * ((6400 + 63) / 64);
  hipLaunchKernelGGL(k_conv3r, dim3(r_0 + r_1 + r_2), dim3(64), 0, stream, a, r_0, r_0 + r_1);
}

// Round 2
// 6359.656 us; speedup vs baseline: 1.7803x; 1.7803x over previous
//
#include <hip/hip_runtime.h>
#include <hip/hip_bf16.h>

#define BSZ 16
#define NCLS 80

// output layout (f32 elements)
#define RO 10752000   // reg/dist offset   = 16*80*8400
#define AO 11289600   // anchors offset    = RO + 16*8400*4
#define SO 11306400   // strides offset    = AO + 8400*2

struct Lvl {
  const float *feat, *cfw, *cfb, *rfw, *rfb, *ccw, *ccb, *rcw, *rcb, *pcw, *pcb, *prw, *prb;
  int C, H, W, HW, pos_off;
  long tcr_off;  // element offset into tc/tr buffers
};

struct Args {
  Lvl l[3];
  float *avg, *gc, *gr;       // [3][BSZ][768] each
  __hip_bfloat16 *tc, *tr;    // concatenated per-level [B,C,HW] bf16
  float *out;
};

__device__ __forceinline__ float sigm(float x) { return 1.f / (1.f + __expf(-x)); }

__device__ __forceinline__ int lvl_of(int bid, int s1, int s2) { return bid >= s2 ? 2 : (bid >= s1 ? 1 : 0); }
__device__ __forceinline__ int loc_of(int bid, int l, int s1, int s2) { return bid - (l == 2 ? s2 : (l == 1 ? s1 : 0)); }

__global__ __launch_bounds__(256) void k_anchor(float* out) {
  int g = blockIdx.x * 256 + threadIdx.x;
  if (g >= 8400) return;
  int l = g < 400 ? 0 : (g < 2000 ? 1 : 2);
  int off = l == 0 ? 0 : (l == 1 ? 400 : 2000);
  int w = l == 0 ? 20 : (l == 1 ? 40 : 80);
  float s = l == 0 ? 32.f : (l == 1 ? 16.f : 8.f);
  int p = g - off;
  int x = p % w, y = p / w;
  out[AO + 2 * g]     = x + 0.5f;
  out[AO + 2 * g + 1] = y + 0.5f;
  out[SO + g]         = s;
}

__global__ __launch_bounds__(256) void k_avg(Args a, int s1, int s2) {
  int bid = blockIdx.x;
  int l = lvl_of(bid, s1, s2);
  int loc = loc_of(bid, l, s1, s2);
  const Lvl& L = a.l[l];
  int c = loc % L.C, b = loc / L.C;
  const float* src = L.feat + (size_t)(b * L.C + c) * L.HW;
  float s = 0.f;
  for (int i = threadIdx.x; i < L.HW; i += 256) s += src[i];
  __shared__ float red[256];
  red[threadIdx.x] = s;
  __syncthreads();
  for (int o = 128; o > 0; o >>= 1) {
    if (threadIdx.x < o) red[threadIdx.x] += red[threadIdx.x + o];
    __syncthreads();
  }
  if (threadIdx.x == 0) a.avg[(l * BSZ + b) * 768 + c] = red[0] / (float)L.HW;
}

__global__ __launch_bounds__(256) void k_gate(Args a, int s1, int s2) {
  int bid = blockIdx.x;
  int l = lvl_of(bid, s1, s2);
  int loc = loc_of(bid, l, s1, s2);
  const Lvl& L = a.l[l];
  int co = loc % L.C, b = loc / L.C;
  const float* av = a.avg + (l * BSZ + b) * 768;
  float sc = 0.f, sr = 0.f;
  for (int ci = threadIdx.x; ci < L.C; ci += 256) {
    float v = av[ci];
    sc += L.cfw[(size_t)co * L.C + ci] * v;
    sr += L.rfw[(size_t)co * L.C + ci] * v;
  }
  __shared__ float rc[256], rr[256];
  rc[threadIdx.x] = sc; rr[threadIdx.x] = sr;
  __syncthreads();
  for (int o = 128; o > 0; o >>= 1) {
    if (threadIdx.x < o) { rc[threadIdx.x] += rc[threadIdx.x + o]; rr[threadIdx.x] += rr[threadIdx.x + o]; }
    __syncthreads();
  }
  if (threadIdx.x == 0) {
    a.gc[(l * BSZ + b) * 768 + co] = sigm(rc[0] + L.cfb[co]);
    a.gr[(l * BSZ + b) * 768 + co] = sigm(rr[0] + L.rfb[co]);
  }
}

// fused dual-branch 1x1 conv: tc = silu(ccw @ (feat*gc) + ccb) + feat ; tr = silu(rcw @ (feat*gr) + rcb)
__global__ __launch_bounds__(256) void k_conv1(Args a, int s1, int s2) {
  int bid = blockIdx.x;
  int l = lvl_of(bid, s1, s2);
  int loc = loc_of(bid, l, s1, s2);
  const Lvl& L = a.l[l];
  int pt = (L.HW + 255) / 256;
  int ptile = loc % pt;
  int t = loc / pt;
  int cochunks = L.C / 16;
  int cc = t % cochunks;
  int b = t / cochunks;
  int p = ptile * 256 + threadIdx.x;
  bool ok = p < L.HW;
  int pp = ok ? p : 0;
  int co0 = cc * 16;

  const float* fbase = L.feat + (size_t)b * L.C * L.HW + pp;
  const float* gcb = a.gc + (l * BSZ + b) * 768;
  const float* grb = a.gr + (l * BSZ + b) * 768;

  float accC[16], accR[16];
#pragma unroll
  for (int j = 0; j < 16; j++) { accC[j] = 0.f; accR[j] = 0.f; }

  const int C = L.C;
#pragma unroll 4
  for (int ci = 0; ci < C; ci++) {
    float f = fbase[(size_t)ci * L.HW];
    float fc = f * gcb[ci];
    float fr = f * grb[ci];
    const float* wc = L.ccw + (size_t)co0 * C + ci;
    const float* wr = L.rcw + (size_t)co0 * C + ci;
#pragma unroll
    for (int j = 0; j < 16; j++) {
      accC[j] += wc[(size_t)j * C] * fc;
      accR[j] += wr[(size_t)j * C] * fr;
    }
  }
  if (ok) {
#pragma unroll
    for (int j = 0; j < 16; j++) {
      float res = fbase[(size_t)(co0 + j) * L.HW];
      float xc = accC[j] + L.ccb[co0 + j];
      float tcv = xc * sigm(xc) + res;
      float xr = accR[j] + L.rcb[co0 + j];
      float trv = xr * sigm(xr);
      size_t o = (size_t)L.tcr_off + ((size_t)(b * L.C + co0 + j)) * L.HW + p;
      a.tc[o] = __float2bfloat16(tcv);
      a.tr[o] = __float2bfloat16(trv);
    }
  }
}

// 3x3 cls pred conv + sigmoid, 16 out channels per thread
__global__ __launch_bounds__(256) void k_conv3c(Args a, int s1, int s2) {
  int bid = blockIdx.x;
  int l = lvl_of(bid, s1, s2);
  int loc = loc_of(bid, l, s1, s2);
  const Lvl& L = a.l[l];
  int pt = (L.HW + 255) / 256;
  int ptile = loc % pt;
  int t = loc / pt;
  int oc = t % 5;
  int b = t / 5;
  int o0 = oc * 16;
  int p = ptile * 256 + threadIdx.x;
  bool ok = p < L.HW;
  int pp = ok ? p : 0;
  int x = pp % L.W, y = pp / L.W;

  int offs[9];
  float mf[9];
#pragma unroll
  for (int ky = 0; ky < 3; ky++)
#pragma unroll
    for (int kx = 0; kx < 3; kx++) {
      int yy = y + ky - 1, xx = x + kx - 1;
      bool v = (yy >= 0 && yy < L.H && xx >= 0 && xx < L.W);
      int yc = min(max(yy, 0), L.H - 1);
      int xc = min(max(xx, 0), L.W - 1);
      offs[ky * 3 + kx] = yc * L.W + xc - pp;
      mf[ky * 3 + kx] = v ? 1.f : 0.f;
    }

  const __hip_bfloat16* base = a.tc + (size_t)L.tcr_off + (size_t)b * L.C * L.HW + pp;
  float acc[16];
#pragma unroll
  for (int j = 0; j < 16; j++) acc[j] = L.pcb[o0 + j];

  const int C = L.C;
  for (int ci = 0; ci < C; ci++) {
    float v[9];
#pragma unroll
    for (int k = 0; k < 9; k++)
      v[k] = __bfloat162float(base[(size_t)ci * L.HW + offs[k]]) * mf[k];
    const float* w = L.pcw + ((size_t)o0 * C + ci) * 9;
#pragma unroll
    for (int j = 0; j < 16; j++) {
      const float* wj = w + (size_t)j * C * 9;
#pragma unroll
      for (int k = 0; k < 9; k++) acc[j] += wj[k] * v[k];
    }
  }
  if (ok) {
#pragma unroll
    for (int j = 0; j < 16; j++)
      a.out[(size_t)(b * NCLS + o0 + j) * 8400 + L.pos_off + p] = sigm(acc[j]);
  }
}

// 3x3 reg pred conv + DFL decode.
// 256 threads = 4 waves; wave w handles DFL group w (17 channels) for 64 positions.
__global__ __launch_bounds__(256) void k_conv3r(Args a, int s1, int s2) {
  int bid = blockIdx.x;
  int l = lvl_of(bid, s1, s2);
  int loc = loc_of(bid, l, s1, s2);
  const Lvl& L = a.l[l];
  int pt = (L.HW + 63) / 64;
  int ptile = loc % pt;
  int b = loc / pt;
  int g4 = threadIdx.x >> 6;       // DFL group 0..3
  int lane = threadIdx.x & 63;
  int p = ptile * 64 + lane;
  bool ok = p < L.HW;
  int pp = ok ? p : 0;
  int x = pp % L.W, y = pp / L.W;

  int offs[9];
  float mf[9];
#pragma unroll
  for (int ky = 0; ky < 3; ky++)
#pragma unroll
    for (int kx = 0; kx < 3; kx++) {
      int yy = y + ky - 1, xx = x + kx - 1;
      bool v = (yy >= 0 && yy < L.H && xx >= 0 && xx < L.W);
      int yc = min(max(yy, 0), L.H - 1);
      int xc = min(max(xx, 0), L.W - 1);
      offs[ky * 3 + kx] = yc * L.W + xc - pp;
      mf[ky * 3 + kx] = v ? 1.f : 0.f;
    }

  const __hip_bfloat16* base = a.tr + (size_t)L.tcr_off + (size_t)b * L.C * L.HW + pp;
  const float* wg = L.prw + (size_t)(g4 * 17) * L.C * 9;   // weights for this group
  float acc[17];
#pragma unroll
  for (int j = 0; j < 17; j++) acc[j] = L.prb[g4 * 17 + j];

  const int C = L.C;
  for (int ci = 0; ci < C; ci++) {
    float v[9];
#pragma unroll
    for (int k = 0; k < 9; k++)
      v[k] = __bfloat162float(base[(size_t)ci * L.HW + offs[k]]) * mf[k];
    const float* w = wg + (size_t)ci * 9;
#pragma unroll
    for (int j = 0; j < 17; j++) {
      const float* wj = w + (size_t)j * C * 9;
#pragma unroll
      for (int k = 0; k < 9; k++) acc[j] += wj[k] * v[k];
    }
  }
  if (ok) {
    float mx = acc[0];
#pragma unroll
    for (int k = 1; k < 17; k++) mx = fmaxf(mx, acc[k]);
    float s = 0.f, d = 0.f;
#pragma unroll
    for (int k = 0; k < 17; k++) {
      float e = __expf(acc[k] - mx);
      s += e;
      d += (float)k * e;
    }
    a.out[RO + ((size_t)b * 8400 + L.pos_off + p) * 4 + g4] = d / s;
  }
}

extern "C" void kernel_launch(void* const* d_in, const int* in_sizes, int n_in,
                              void* d_out, int out_size, void* d_ws, size_t ws_size,
                              hipStream_t stream) {
  static const int Cs[3] = {768, 384, 192};
  static const int HHs[3] = {20, 40, 80};
  static const int POs[3] = {0, 400, 2000};
  static const long TOFF[3] = {0, 4915200, 14745600};

  Args a;
  for (int l = 0; l < 3; l++) {
    const float* const* p = (const float* const*)(d_in + l * 13);
    Lvl& L = a.l[l];
    L.feat = p[0];
    L.cfw = p[1]; L.cfb = p[2]; L.rfw = p[3]; L.rfb = p[4];
    L.ccw = p[5]; L.ccb = p[6]; L.rcw = p[7]; L.rcb = p[8];
    L.pcw = p[9]; L.pcb = p[10]; L.prw = p[11]; L.prb = p[12];
    L.C = Cs[l]; L.H = HHs[l]; L.W = HHs[l]; L.HW = HHs[l] * HHs[l];
    L.pos_off = POs[l];
    L.tcr_off = TOFF[l];
  }
  float* ws = (float*)d_ws;
  a.avg = ws;
  a.gc = ws + 3 * BSZ * 768;
  a.gr = ws + 2 * 3 * BSZ * 768;
  a.tc = (__hip_bfloat16*)(ws + 3 * 3 * BSZ * 768);
  a.tr = a.tc + 34406400;
  a.out = (float*)d_out;

  hipLaunchKernelGGL(k_anchor, dim3(33), dim3(256), 0, stream, a.out);

  int s1 = BSZ * 768, s2 = s1 + BSZ * 384, tot = s2 + BSZ * 192;
  hipLaunchKernelGGL(k_avg, dim3(tot), dim3(256), 0, stream, a, s1, s2);
  hipLaunchKernelGGL(k_gate, dim3(tot), dim3(256), 0, stream, a, s1, s2);

  int c1_0 = BSZ * (768 / 16) * ((400 + 255) / 256);
  int c1_1 = BSZ * (384 / 16) * ((1600 + 255) / 256);
  int c1_2 = BSZ * (192 / 16) * ((6400 + 255) / 256);
  hipLaunchKernelGGL(k_conv1, dim3(c1_0 + c1_1 + c1_2), dim3(256), 0, stream, a, c1_0, c1_0 + c1_1);

  int c3_0 = BSZ * 5 * ((400 + 255) / 256);
  int c3_1 = BSZ * 5 * ((1600 + 255) / 256);
  int c3_2 = BSZ * 5 * ((6400 + 255) / 256);
  hipLaunchKernelGGL(k_conv3c, dim3(c3_0 + c3_1 + c3_2), dim3(256), 0, stream, a, c3_0, c3_0 + c3_1);

  int r_0 = BSZ * ((400 + 63) / 64);
  int r_1 = BSZ * ((1600 + 63) / 64);
  int r_2 = BSZ * ((6400 + 63) / 64);
  hipLaunchKernelGGL(k_conv3r, dim3(r_0 + r_1 + r_2), dim3(256), 0, stream, a, r_0, r_0 + r_1);
}

// Round 3
// 597.905 us; speedup vs baseline: 18.9360x; 10.6366x over previous
//
#include <hip/hip_runtime.h>
#include <hip/hip_bf16.h>

typedef __attribute__((ext_vector_type(8))) short bf16x8;
typedef __attribute__((ext_vector_type(4))) float f32x4;
typedef __attribute__((ext_vector_type(4))) unsigned short u16x4;
typedef unsigned short u16;
typedef unsigned int u32;

#define BSZ 16
#define RO 10752000
#define AO 11289600
#define SO 11306400

__device__ __forceinline__ float sigm(float x) { return 1.f / (1.f + __expf(-x)); }

__device__ __forceinline__ u16 f2bf(float f) {
  u32 u = __float_as_uint(f);
  u = u + 0x7FFF + ((u >> 16) & 1);
  return (u16)(u >> 16);
}

__device__ __forceinline__ void gll16(const void* g, void* l) {
  __builtin_amdgcn_global_load_lds((const __attribute__((address_space(1))) void*)g,
                                   (__attribute__((address_space(3))) void*)l, 16, 0, 0);
}

// ---------------- anchors ----------------
__global__ __launch_bounds__(256) void k_anchor(float* out) {
  int g = blockIdx.x * 256 + threadIdx.x;
  if (g >= 8400) return;
  int l = g < 400 ? 0 : (g < 2000 ? 1 : 2);
  int off = l == 0 ? 0 : (l == 1 ? 400 : 2000);
  int w = 20 << l;
  float s = (float)(32 >> l);
  int p = g - off;
  int x = p % w, y = p / w;
  out[AO + 2 * g] = x + 0.5f;
  out[AO + 2 * g + 1] = y + 0.5f;
  out[SO + g] = s;
}

// ---------------- avg pool ----------------
struct SmallArgs {
  const float* feat[3];
  const float *cfw[3], *cfb[3], *rfw[3], *rfb[3];
  float *avg, *gc, *gr;
};

__global__ __launch_bounds__(256) void k_avg(SmallArgs A, int s1, int s2) {
  int bid = blockIdx.x;
  int l = bid >= s2 ? 2 : (bid >= s1 ? 1 : 0);
  int loc = bid - (l == 2 ? s2 : (l == 1 ? s1 : 0));
  int C = 768 >> l, HW = 400 << (2 * l);
  int c = loc % C, b = loc / C;
  const float* src = A.feat[l] + (size_t)(b * C + c) * HW;
  float s = 0.f;
  for (int i = threadIdx.x; i < HW; i += 256) s += src[i];
  __shared__ float red[256];
  red[threadIdx.x] = s;
  __syncthreads();
  for (int o = 128; o > 0; o >>= 1) {
    if (threadIdx.x < o) red[threadIdx.x] += red[threadIdx.x + o];
    __syncthreads();
  }
  if (threadIdx.x == 0) A.avg[(l * BSZ + b) * 768 + c] = red[0] / (float)HW;
}

// ---------------- gates ----------------
__global__ __launch_bounds__(256) void k_gate(SmallArgs A, int s1, int s2) {
  int bid = blockIdx.x;
  int l = bid >= s2 ? 2 : (bid >= s1 ? 1 : 0);
  int loc = bid - (l == 2 ? s2 : (l == 1 ? s1 : 0));
  int C = 768 >> l;
  int co = loc % C, b = loc / C;
  const float* av = A.avg + (l * BSZ + b) * 768;
  float sc = 0.f, sr = 0.f;
  for (int ci = threadIdx.x; ci < C; ci += 256) {
    float v = av[ci];
    sc += A.cfw[l][(size_t)co * C + ci] * v;
    sr += A.rfw[l][(size_t)co * C + ci] * v;
  }
  __shared__ float rc[256], rr[256];
  rc[threadIdx.x] = sc; rr[threadIdx.x] = sr;
  __syncthreads();
  for (int o = 128; o > 0; o >>= 1) {
    if (threadIdx.x < o) { rc[threadIdx.x] += rc[threadIdx.x + o]; rr[threadIdx.x] += rr[threadIdx.x + o]; }
    __syncthreads();
  }
  if (threadIdx.x == 0) {
    A.gc[(l * BSZ + b) * 768 + co] = sigm(rc[0] + A.cfb[l][co]);
    A.gr[(l * BSZ + b) * 768 + co] = sigm(rr[0] + A.rfb[l][co]);
  }
}

// ---------------- weight pre-transpose: wT[t][96][C] (pad rows pre-zeroed) ----------------
__global__ __launch_bounds__(256) void k_wprep(const float* w, u16* dst, int C) {
  int id = blockIdx.x * 256 + threadIdx.x;
  int co = id / C, ci = id - co * C;
  const float* s = w + (size_t)id * 9;
#pragma unroll
  for (int t = 0; t < 9; t++) dst[((size_t)(t * 96 + co)) * C + ci] = f2bf(s[t]);
}

// ---------------- conv1: dual-branch 1x1 MFMA GEMM ----------------
// M=64 (co tile), N=128 (positions), K=C. Gate folded into A. Outputs tcT/trT [b][p][C] bf16.
struct C1Lvl {
  const float *feat, *w0, *b0, *w1, *b1, *gc, *gr;
  u16 *tcT, *trT;
  int C, HW, ntiles, mblks, bstart;
};
struct C1Args { C1Lvl l[3]; };

__global__ __launch_bounds__(256) void k_conv1(C1Args A) {
  __shared__ char smem[32768];  // A0 8K | A1 8K | B 16K
  int bid = blockIdx.x;
  int li = (bid >= A.l[2].bstart) ? 2 : (bid >= A.l[1].bstart ? 1 : 0);
  const C1Lvl& L = A.l[li];
  int loc = bid - L.bstart;
  int mb = loc % L.mblks;
  int t2 = loc / L.mblks;
  int nt = t2 % L.ntiles;
  int b = t2 / L.ntiles;
  const int C = L.C, HW = L.HW;
  int p0 = nt * 128, co0 = mb * 64;
  int tid = threadIdx.x, lane = tid & 63, w = tid >> 6;
  int wm = w >> 1, wn = w & 1;
  char* A0 = smem;
  char* A1 = smem + 8192;
  char* Bb = smem + 16384;
  const float* gate0 = L.gc + b * 768;
  const float* gate1 = L.gr + b * 768;
  const float* feat_b = L.feat + (size_t)b * C * HW;
  int sk = tid >> 2, sq = tid & 3;  // B staging: channel sk, p-quarter sq

  f32x4 acc0[2][4], acc1[2][4];
#pragma unroll
  for (int mi = 0; mi < 2; mi++)
#pragma unroll
    for (int ni = 0; ni < 4; ni++) { acc0[mi][ni] = (f32x4){0.f,0.f,0.f,0.f}; acc1[mi][ni] = (f32x4){0.f,0.f,0.f,0.f}; }

  const int nchunk = C >> 6;
  for (int c = 0; c < nchunk; c++) {
    int ci0 = c << 6;
    // ---- stage A (both branches): 2 units of 8 elems per thread per branch
#pragma unroll
    for (int g = 0; g < 2; g++) {
      int u = g * 256 + tid;
      int m = u >> 3, s = u & 7;
      const float* wr0 = L.w0 + (size_t)(co0 + m) * C + ci0 + s * 8;
      const float* wr1 = L.w1 + (size_t)(co0 + m) * C + ci0 + s * 8;
      const float* g0 = gate0 + ci0 + s * 8;
      const float* g1 = gate1 + ci0 + s * 8;
      bf16x8 h0, h1;
#pragma unroll
      for (int j = 0; j < 8; j++) {
        h0[j] = (short)f2bf(wr0[j] * g0[j]);
        h1[j] = (short)f2bf(wr1[j] * g1[j]);
      }
      int off = m * 128 + ((s ^ (m & 7)) << 4);
      *(bf16x8*)(A0 + off) = h0;
      *(bf16x8*)(A1 + off) = h1;
    }
    // ---- stage B: feat f32 -> bf16, transposed [n][k], swizzled
    {
      const float* sp = feat_b + (size_t)(ci0 + sk) * HW + p0 + sq * 32;
      int wbase = ((sk >> 3) ^ 0) ;  // placeholder to keep compiler happy
      (void)wbase;
      if (p0 + 128 <= HW) {
#pragma unroll
        for (int j4 = 0; j4 < 8; j4++) {
          f32x4 v = *(const f32x4*)(sp + j4 * 4);
#pragma unroll
          for (int e = 0; e < 4; e++) {
            int n = sq * 32 + j4 * 4 + e;
            *(u16*)(Bb + n * 128 + (((sk >> 3) ^ (n & 7)) << 4) + ((sk & 7) << 1)) = f2bf(v[e]);
          }
        }
      } else {
#pragma unroll
        for (int j = 0; j < 32; j++) {
          int p = p0 + sq * 32 + j;
          float v = (p < HW) ? sp[j] : 0.f;
          int n = sq * 32 + j;
          *(u16*)(Bb + n * 128 + (((sk >> 3) ^ (n & 7)) << 4) + ((sk & 7) << 1)) = f2bf(v);
        }
      }
    }
    __syncthreads();
    // ---- MFMA
#pragma unroll
    for (int ks = 0; ks < 2; ks++) {
      int sl = ks * 4 + (lane >> 4);
      bf16x8 a0[2], a1[2], bfr[4];
#pragma unroll
      for (int mi = 0; mi < 2; mi++) {
        int row = wm * 32 + mi * 16 + (lane & 15);
        int off = row * 128 + ((sl ^ (row & 7)) << 4);
        a0[mi] = *(const bf16x8*)(A0 + off);
        a1[mi] = *(const bf16x8*)(A1 + off);
      }
#pragma unroll
      for (int ni = 0; ni < 4; ni++) {
        int row = wn * 64 + ni * 16 + (lane & 15);
        bfr[ni] = *(const bf16x8*)(Bb + row * 128 + ((sl ^ (row & 7)) << 4));
      }
#pragma unroll
      for (int mi = 0; mi < 2; mi++)
#pragma unroll
        for (int ni = 0; ni < 4; ni++) {
          acc0[mi][ni] = __builtin_amdgcn_mfma_f32_16x16x32_bf16(a0[mi], bfr[ni], acc0[mi][ni], 0, 0, 0);
          acc1[mi][ni] = __builtin_amdgcn_mfma_f32_16x16x32_bf16(a1[mi], bfr[ni], acc1[mi][ni], 0, 0, 0);
        }
    }
    __syncthreads();
  }
  // ---- epilogue: silu(+bias), cls adds residual feat; store bf16 to [b][p][C]
#pragma unroll
  for (int mi = 0; mi < 2; mi++) {
    int cob = co0 + wm * 32 + mi * 16 + ((lane >> 4) << 2);
    f32x4 bia0 = *(const f32x4*)(L.b0 + cob);
    f32x4 bia1 = *(const f32x4*)(L.b1 + cob);
#pragma unroll
    for (int ni = 0; ni < 4; ni++) {
      int n = wn * 64 + ni * 16 + (lane & 15);
      int p = p0 + n;
      if (p >= HW) continue;
      u16x4 o0, o1;
#pragma unroll
      for (int j = 0; j < 4; j++) {
        float x0 = acc0[mi][ni][j] + bia0[j];
        float r = feat_b[(size_t)(cob + j) * HW + p];
        o0[j] = f2bf(x0 * sigm(x0) + r);
        float x1 = acc1[mi][ni][j] + bia1[j];
        o1[j] = f2bf(x1 * sigm(x1));
      }
      size_t off = ((size_t)b * HW + p) * C + cob;
      *(u16x4*)(L.tcT + off) = o0;
      *(u16x4*)(L.trT + off) = o1;
    }
  }
}

// ---------------- conv3: 3x3 MFMA implicit GEMM (tap-outer), M=96 N=128 K=C per tap ----------------
struct C3Lvl {
  const u16* inT;       // [b][p][C] bf16 level base
  const float* w;       // OIHW f32 (fallback)
  const u16* wT;        // [t][96][C] bf16 (if WT)
  const float* bias;
  int C, W, H, HW, ntiles, bstart, pos_off;
};
struct C3Args { C3Lvl l[3]; const u16* zp; float* out; };

template<int MREAL, int EPI, bool WT>
__global__ __launch_bounds__(256) void k_conv3(C3Args A) {
  __shared__ char smem[EPI == 3 ? 34816 : 28672];  // A 12K | B 16K  (reg: union with P[128][68] f32)
  char* Ab = smem;
  char* Bb = smem + 12288;
  int bid = blockIdx.x;
  int li = (bid >= A.l[2].bstart) ? 2 : (bid >= A.l[1].bstart ? 1 : 0);
  const C3Lvl& L = A.l[li];
  int loc = bid - L.bstart;
  int nt = loc % L.ntiles;
  int b = loc / L.ntiles;
  const int C = L.C, W = L.W, H = L.H, HW = L.HW;
  int p0 = nt * 128;
  int tid = threadIdx.x, lane = tid & 63, w = tid >> 6;
  int wm = w >> 1, wn = w & 1;
  int sl8 = lane & 7;
  const u16* inb = L.inT + (size_t)b * HW * C;

  // per-thread B staging rows (4 gll of 8 rows per wave)
  int rr[4], px[4], py[4];
  bool pv[4];
#pragma unroll
  for (int i = 0; i < 4; i++) {
    int r = w * 32 + i * 8 + (lane >> 3);
    rr[i] = r;
    int p = p0 + r;
    pv[i] = p < HW;
    int pp = pv[i] ? p : 0;
    px[i] = pp % W;
    py[i] = pp / W;
  }

  f32x4 acc[3][4];
#pragma unroll
  for (int mi = 0; mi < 3; mi++)
#pragma unroll
    for (int ni = 0; ni < 4; ni++) acc[mi][ni] = (f32x4){0.f,0.f,0.f,0.f};

  const int nchunk = C >> 6;
  for (int t = 0; t < 9; t++) {
    int dy = t / 3 - 1, dx = t - (t / 3) * 3 - 1;
    const u16* bs[4];
    bool bv[4];
#pragma unroll
    for (int i = 0; i < 4; i++) {
      int xx = px[i] + dx, yy = py[i] + dy;
      bool ok = pv[i] && ((unsigned)xx < (unsigned)W) && ((unsigned)yy < (unsigned)H);
      bv[i] = ok;
      int q = p0 + rr[i] + dy * W + dx;
      bs[i] = ok ? (inb + (size_t)q * C + ((sl8 ^ (rr[i] & 7)) << 3)) : A.zp;
    }
    for (int c = 0; c < nchunk; c++) {
      int ci0 = c << 6;
      // ---- stage A
      if (WT) {
        const u16* wl = L.wT;
#pragma unroll
        for (int g = 0; g < 3; g++) {
          int row = w * 24 + g * 8 + (lane >> 3);
          const u16* src = wl + ((size_t)(t * 96 + row)) * C + ci0 + ((sl8 ^ (row & 7)) << 3);
          gll16(src, Ab + (w * 24 + g * 8) * 128);
        }
      } else {
#pragma unroll
        for (int g = 0; g < 3; g++) {
          int u = g * 256 + tid;
          int am = u >> 3, as = u & 7;
          bf16x8 h;
          if (am < MREAL) {
            const float* wp = L.w + ((size_t)am * C + ci0 + as * 8) * 9 + t;
#pragma unroll
            for (int j = 0; j < 8; j++) h[j] = (short)f2bf(wp[j * 9]);
          } else {
#pragma unroll
            for (int j = 0; j < 8; j++) h[j] = 0;
          }
          *(bf16x8*)(Ab + am * 128 + ((as ^ (am & 7)) << 4)) = h;
        }
      }
      // ---- stage B via global_load_lds (pre-swizzled source, zeropage for invalid)
#pragma unroll
      for (int i = 0; i < 4; i++) {
        const void* src = bv[i] ? (const void*)(bs[i] + ci0) : (const void*)A.zp;
        gll16(src, Bb + (w * 32 + i * 8) * 128);
      }
      __syncthreads();
      // ---- MFMA
#pragma unroll
      for (int ks = 0; ks < 2; ks++) {
        int sl = ks * 4 + (lane >> 4);
        bf16x8 af[3], bfr[4];
#pragma unroll
        for (int mi = 0; mi < 3; mi++) {
          int row = wm * 48 + mi * 16 + (lane & 15);
          af[mi] = *(const bf16x8*)(Ab + row * 128 + ((sl ^ (row & 7)) << 4));
        }
#pragma unroll
        for (int ni = 0; ni < 4; ni++) {
          int row = wn * 64 + ni * 16 + (lane & 15);
          bfr[ni] = *(const bf16x8*)(Bb + row * 128 + ((sl ^ (row & 7)) << 4));
        }
#pragma unroll
        for (int mi = 0; mi < 3; mi++)
#pragma unroll
          for (int ni = 0; ni < 4; ni++)
            acc[mi][ni] = __builtin_amdgcn_mfma_f32_16x16x32_bf16(af[mi], bfr[ni], acc[mi][ni], 0, 0, 0);
      }
      __syncthreads();
    }
  }

  if (EPI == 2) {
    // cls: sigmoid -> out [b][80][8400]
#pragma unroll
    for (int mi = 0; mi < 3; mi++) {
      int cob = wm * 48 + mi * 16 + ((lane >> 4) << 2);
      if (cob >= 80) continue;
      f32x4 bia = *(const f32x4*)(L.bias + cob);
#pragma unroll
      for (int ni = 0; ni < 4; ni++) {
        int n = wn * 64 + ni * 16 + (lane & 15);
        int p = p0 + n;
        if (p >= HW) continue;
#pragma unroll
        for (int j = 0; j < 4; j++) {
          A.out[(size_t)(b * 80 + cob + j) * 8400 + L.pos_off + p] = sigm(acc[mi][ni][j] + bia[j]);
        }
      }
    }
  } else {
    // reg: DFL softmax-decode through LDS
    float* P = (float*)smem;  // [128][68]
#pragma unroll
    for (int mi = 0; mi < 3; mi++) {
      int cob = wm * 48 + mi * 16 + ((lane >> 4) << 2);
      if (cob < 68) {
        f32x4 bia = *(const f32x4*)(L.bias + cob);
#pragma unroll
        for (int ni = 0; ni < 4; ni++) {
          int n = wn * 64 + ni * 16 + (lane & 15);
          f32x4 v = acc[mi][ni];
#pragma unroll
          for (int j = 0; j < 4; j++) v[j] += bia[j];
          *(f32x4*)(P + n * 68 + cob) = v;
        }
      }
    }
    __syncthreads();
    int n = tid >> 1, g2 = tid & 1;
    int p = p0 + n;
    if (p < HW) {
      float d[2];
#pragma unroll
      for (int gg = 0; gg < 2; gg++) {
        const float* row = P + n * 68 + (g2 * 2 + gg) * 17;
        float mx = row[0];
#pragma unroll
        for (int k = 1; k < 17; k++) mx = fmaxf(mx, row[k]);
        float sum = 0.f, dot = 0.f;
#pragma unroll
        for (int k = 0; k < 17; k++) {
          float e = __expf(row[k] - mx);
          sum += e;
          dot += (float)k * e;
        }
        d[gg] = dot / sum;
      }
      float2 dv = make_float2(d[0], d[1]);
      *(float2*)(A.out + RO + ((size_t)b * 8400 + L.pos_off + p) * 4 + g2 * 2) = dv;
    }
  }
}

// ---------------- host ----------------
extern "C" void kernel_launch(void* const* d_in, const int* in_sizes, int n_in,
                              void* d_out, int out_size, void* d_ws, size_t ws_size,
                              hipStream_t stream) {
  static const int Cs[3] = {768, 384, 192};
  static const int HWs[3] = {400, 1600, 6400};
  static const int Ws[3] = {20, 40, 80};
  static const int POs[3] = {0, 400, 2000};
  static const long TOFF[3] = {0, 4915200, 14745600};
  static const long WTOFF[3] = {0, 663552, 995328};
  static const int NT[3] = {4, 13, 50};     // ceil(HW/128)
  static const int MB[3] = {12, 6, 3};      // C/64

  char* wsb = (char*)d_ws;
  u16* zp = (u16*)wsb;                       // 256 B zeropage
  float* avg = (float*)(wsb + 256);
  float* gc = avg + 3 * BSZ * 768;
  float* gr = gc + 3 * BSZ * 768;
  u16* tcT = (u16*)(gr + 3 * BSZ * 768);
  u16* trT = tcT + 34406400;
  u16* wTc = trT + 34406400;
  u16* wTr = wTc + 1161216;
  const size_t NEED_WT = 256 + 3 * (size_t)BSZ * 768 * 4 * 3 + 2 * 34406400ull * 2 + 2 * 1161216ull * 2;
  bool useWT = ws_size >= NEED_WT;

  hipMemsetAsync(zp, 0, 256, stream);

  SmallArgs SA;
  for (int l = 0; l < 3; l++) {
    const float* const* p = (const float* const*)(d_in + l * 13);
    SA.feat[l] = p[0];
    SA.cfw[l] = p[1]; SA.cfb[l] = p[2];
    SA.rfw[l] = p[3]; SA.rfb[l] = p[4];
  }
  SA.avg = avg; SA.gc = gc; SA.gr = gr;

  if (useWT) {
    hipMemsetAsync(wTc, 0, 2 * 1161216ull * 2, stream);
    for (int l = 0; l < 3; l++) {
      const float* pcw = (const float*)d_in[l * 13 + 9];
      const float* prw = (const float*)d_in[l * 13 + 11];
      hipLaunchKernelGGL(k_wprep, dim3(80 * Cs[l] / 256), dim3(256), 0, stream, pcw, wTc + WTOFF[l], Cs[l]);
      hipLaunchKernelGGL(k_wprep, dim3(68 * Cs[l] / 256), dim3(256), 0, stream, prw, wTr + WTOFF[l], Cs[l]);
    }
  }

  int s1 = BSZ * 768, s2 = s1 + BSZ * 384, tot = s2 + BSZ * 192;
  hipLaunchKernelGGL(k_avg, dim3(tot), dim3(256), 0, stream, SA, s1, s2);
  hipLaunchKernelGGL(k_gate, dim3(tot), dim3(256), 0, stream, SA, s1, s2);

  C1Args C1;
  int bstart = 0;
  for (int l = 0; l < 3; l++) {
    const float* const* p = (const float* const*)(d_in + l * 13);
    C1Lvl& L = C1.l[l];
    L.feat = p[0];
    L.w0 = p[5]; L.b0 = p[6];   // ccw/ccb
    L.w1 = p[7]; L.b1 = p[8];   // rcw/rcb
    L.gc = gc + l * BSZ * 768;
    L.gr = gr + l * BSZ * 768;
    L.tcT = tcT + TOFF[l];
    L.trT = trT + TOFF[l];
    L.C = Cs[l]; L.HW = HWs[l]; L.ntiles = NT[l]; L.mblks = MB[l];
    L.bstart = bstart;
    bstart += BSZ * NT[l] * MB[l];
  }
  hipLaunchKernelGGL(k_conv1, dim3(bstart), dim3(256), 0, stream, C1);

  C3Args C3c, C3r;
  int bs3 = 0;
  for (int l = 0; l < 3; l++) {
    const float* const* p = (const float* const*)(d_in + l * 13);
    C3Lvl Lc, Lr;
    Lc.inT = tcT + TOFF[l]; Lc.w = p[9]; Lc.wT = wTc + WTOFF[l]; Lc.bias = p[10];
    Lr.inT = trT + TOFF[l]; Lr.w = p[11]; Lr.wT = wTr + WTOFF[l]; Lr.bias = p[12];
    Lc.C = Lr.C = Cs[l]; Lc.W = Lr.W = Ws[l]; Lc.H = Lr.H = Ws[l]; Lc.HW = Lr.HW = HWs[l];
    Lc.ntiles = Lr.ntiles = NT[l];
    Lc.bstart = Lr.bstart = bs3;
    Lc.pos_off = Lr.pos_off = POs[l];
    C3c.l[l] = Lc; C3r.l[l] = Lr;
    bs3 += BSZ * NT[l];
  }
  C3c.zp = zp; C3c.out = (float*)d_out;
  C3r.zp = zp; C3r.out = (float*)d_out;

  if (useWT) {
    hipLaunchKernelGGL((k_conv3<80, 2, true>), dim3(bs3), dim3(256), 0, stream, C3c);
    hipLaunchKernelGGL((k_conv3<68, 3, true>), dim3(bs3), dim3(256), 0, stream, C3r);
  } else {
    hipLaunchKernelGGL((k_conv3<80, 2, false>), dim3(bs3), dim3(256), 0, stream, C3c);
    hipLaunchKernelGGL((k_conv3<68, 3, false>), dim3(bs3), dim3(256), 0, stream, C3r);
  }

  hipLaunchKernelGGL(k_anchor, dim3(33), dim3(256), 0, stream, (float*)d_out);
}